// Round 7
// baseline (447.955 us; speedup 1.0000x reference)
//
#include <hip/hip_runtime.h>
#include <math.h>

typedef __attribute__((ext_vector_type(8))) short bf16x8;
typedef __attribute__((ext_vector_type(4))) float f32x4;
typedef __attribute__((ext_vector_type(4))) unsigned short us4;
typedef __attribute__((ext_vector_type(8))) unsigned short us8;

static constexpr int kN  = 50000;
static constexpr int kE  = 800000;
static constexpr int kNBUK = 98;     // ceil(50000/512), bucket = dst>>9
static constexpr int kCAP  = 9216;   // per-bucket payload cap (mean 8163 + 11.6 sigma)

__device__ __forceinline__ float b2f(unsigned short u) {
  union { unsigned u; float f; } x; x.u = ((unsigned)u) << 16; return x.f;
}
__device__ __forceinline__ unsigned short f2b(float f) {
  union { float f; unsigned u; } x; x.f = f;
  unsigned u = x.u;
  unsigned r = (u + 0x7fffu + ((u >> 16) & 1u)) >> 16;
  return (unsigned short)r;
}

// ---------------- fused prep: Wt_a, Wt_b (bf16 [256][256]), W1T (bf16 [128][256])
__global__ __launch_bounds__(256)
void k_prep(const float* __restrict__ Wa, const float* __restrict__ Wb,
            const float* __restrict__ W1,
            unsigned short* __restrict__ wta, unsigned short* __restrict__ wtb,
            unsigned short* __restrict__ w1t) {
  int b = blockIdx.x, t = threadIdx.x;
  if (b < 256) {
    int i = b * 256 + t, j = i >> 8, k = i & 255;
    wta[j * 256 + k] = f2b(Wa[k * 256 + j]);
  } else if (b < 512) {
    int i = (b - 256) * 256 + t, j = i >> 8, k = i & 255;
    wtb[j * 256 + k] = f2b(Wb[k * 256 + j]);
  } else {
    int i = (b - 512) * 256 + t, j = i >> 8, k = i & 255;  // j<128
    w1t[j * 256 + k] = f2b(W1[k * 128 + j]);
  }
}

// ---------------- feat = h @ W for BOTH metapaths, single h read -----------
// launch_bounds (512,2): the old (512,4) bound capped VGPR at 128 and could
// force silent spills (scratch traffic invisible in the byte model). LDS
// (72KB -> 2 blocks/CU) caps occupancy anyway, so nothing is lost.
__global__ __launch_bounds__(512, 2)
void k_gemm(const float* __restrict__ h,
            const unsigned short* __restrict__ wta,
            const unsigned short* __restrict__ wtb,
            const float* __restrict__ ala, const float* __restrict__ ara,
            const float* __restrict__ alb, const float* __restrict__ arb,
            unsigned short* __restrict__ fa, unsigned short* __restrict__ fb,
            float* __restrict__ ela, float* __restrict__ era,
            float* __restrict__ elb, float* __restrict__ erb) {
  __shared__ us8 la[64 * 8];                   // 8KB
  __shared__ us8 lb[2][256 * 8];               // 64KB
  const int m0 = blockIdx.x * 64;
  const int t = threadIdx.x;
  const int lane = t & 63;
  const int wave = t >> 6;                     // 0..7
  const int z = wave >> 2;                     // metapath
  const int col = lane & 15;
  const int quad = lane >> 4;
  const int nw = (wave & 3) * 64;              // 0,64,128,192
  unsigned short* f = z ? fb : fa;
  const float* al = z ? alb : ala;
  const float* ar = z ? arb : ara;
  float* el = z ? elb : ela;
  float* er = z ? erb : era;
  f32x4 acc[4][4];
#pragma unroll
  for (int i = 0; i < 4; ++i)
#pragma unroll
    for (int j = 0; j < 4; ++j) acc[i][j] = (f32x4){0.f, 0.f, 0.f, 0.f};

  for (int ks = 0; ks < 4; ++ks) {
    const int k0 = ks * 64;
    __syncthreads();
    // stage A: 64 rows x 64 k, fp32 -> bf16. 1024 f32x4 units, 2 iters.
#pragma unroll
    for (int i = 0; i < 2; ++i) {
      int idx = i * 512 + t;
      int r = idx >> 4, g = (idx >> 1) & 7, half = idx & 1;
      int gr = m0 + r;
      f32x4 v = {0.f, 0.f, 0.f, 0.f};
      if (gr < kN) v = *(const f32x4*)(h + (size_t)gr * 256 + k0 + g * 8 + half * 4);
      us4 o;
      o.x = f2b(v.x); o.y = f2b(v.y); o.z = f2b(v.z); o.w = f2b(v.w);
      *(us4*)((unsigned short*)&la[r * 8 + (g ^ (r & 7))] + half * 4) = o;
    }
    // stage B both metapaths: 2 x 2048 16B-units, 8 iters.
#pragma unroll
    for (int i = 0; i < 8; ++i) {
      int idx = i * 512 + t;
      int zz = idx >> 11;
      int id2 = idx & 2047;
      int r = id2 >> 3, g = id2 & 7;
      const unsigned short* w = zz ? wtb : wta;
      lb[zz][r * 8 + (g ^ (r & 7))] = *(const us8*)(w + r * 256 + k0 + g * 8);
    }
    __syncthreads();
#pragma unroll
    for (int k32 = 0; k32 < 64; k32 += 32) {
      const int cg = (k32 >> 3) + quad;
      bf16x8 af[4], bf[4];
#pragma unroll
      for (int s = 0; s < 4; ++s) {
        int arow = s * 16 + col;
        af[s] = (bf16x8)la[arow * 8 + (cg ^ (arow & 7))];
        int brow = nw + s * 16 + col;
        bf[s] = (bf16x8)lb[z][brow * 8 + (cg ^ (brow & 7))];
      }
#pragma unroll
      for (int i = 0; i < 4; ++i)
#pragma unroll
        for (int j = 0; j < 4; ++j)
          acc[i][j] = __builtin_amdgcn_mfma_f32_16x16x32_bf16(af[i], bf[j],
                                                              acc[i][j], 0, 0, 0);
    }
  }
  // epilogue 1: feat store (C row = quad*4+reg, col = lane&15)
#pragma unroll
  for (int i = 0; i < 4; ++i) {
#pragma unroll
    for (int r = 0; r < 4; ++r) {
      int row = m0 + i * 16 + quad * 4 + r;
      if (row < kN) {
#pragma unroll
        for (int j = 0; j < 4; ++j)
          f[(size_t)row * 256 + nw + j * 16 + col] = f2b(acc[i][j][r]);
      }
    }
  }
  // epilogue 2: el/er for this wave's 2 heads of its metapath
  float alv[4], arv[4];
#pragma unroll
  for (int j = 0; j < 4; ++j) {
    alv[j] = al[nw + j * 16 + col];
    arv[j] = ar[nw + j * 16 + col];
  }
  const int hA = nw >> 5;
#pragma unroll
  for (int i = 0; i < 4; ++i) {
#pragma unroll
    for (int r = 0; r < 4; ++r) {
      float pAl = acc[i][0][r] * alv[0] + acc[i][1][r] * alv[1];
      float pBl = acc[i][2][r] * alv[2] + acc[i][3][r] * alv[3];
      float pAr = acc[i][0][r] * arv[0] + acc[i][1][r] * arv[1];
      float pBr = acc[i][2][r] * arv[2] + acc[i][3][r] * arv[3];
#pragma unroll
      for (int off = 1; off < 16; off <<= 1) {
        pAl += __shfl_xor(pAl, off);
        pBl += __shfl_xor(pBl, off);
        pAr += __shfl_xor(pAr, off);
        pBr += __shfl_xor(pBr, off);
      }
      int row = m0 + i * 16 + quad * 4 + r;
      if (col == 0 && row < kN) {
        el[row * 8 + hA] = pAl;
        el[row * 8 + hA + 1] = pBl;
        er[row * 8 + hA] = pAr;
        er[row * 8 + hA + 1] = pBr;
      }
    }
  }
}

// ---------------- CSR build via radix partition ----------------------------
__global__ __launch_bounds__(256)
void k_part(const int* __restrict__ sa, const int* __restrict__ da,
            const int* __restrict__ sb, const int* __restrict__ db,
            int* __restrict__ cnt, unsigned* __restrict__ pay) {
  int y = blockIdx.y;
  const int* s = y ? sb : sa;
  const int* d = y ? db : da;
  unsigned* p = pay + (size_t)y * kNBUK * kCAP;
  int* cn = cnt + y * kNBUK;
  __shared__ unsigned stash[6400];              // 25.6KB
  __shared__ int h[kNBUK];
  int t = threadIdx.x;
  if (t < kNBUK) h[t] = 0;
  __syncthreads();
  int e0 = blockIdx.x * 6400;
#pragma unroll 5
  for (int it = 0; it < 25; ++it) {
    int e = e0 + it * 256 + t;
    int sv = s[e], dv = d[e];
    int b = dv >> 9;
    stash[it * 256 + t] = (unsigned)sv | ((unsigned)(dv & 511) << 16) |
                          ((unsigned)b << 25);
    atomicAdd(&h[b], 1);
  }
  __syncthreads();
  if (t < kNBUK) h[t] = atomicAdd(&cn[t], h[t]);  // h becomes block's cursor
  __syncthreads();
#pragma unroll 5
  for (int it = 0; it < 25; ++it) {
    unsigned w = stash[it * 256 + t];
    int b = w >> 25;
    int slot = atomicAdd(&h[b], 1);
    p[b * kCAP + slot] = w & 0x1FFFFFFu;
  }
}

// k_bscan: exclusive scan of 2x98 bucket counts -> global es/rp bases.
__global__ __launch_bounds__(256)
void k_bscan(const int* __restrict__ cnt, int* __restrict__ bbase,
             int* __restrict__ rpa, int* __restrict__ rpb) {
  __shared__ int buf[2][128];
  int t = threadIdx.x;
  int y = t >> 7, i = t & 127;
  int x = (i < kNBUK) ? cnt[y * kNBUK + i] : 0;
  buf[y][i] = x;
  __syncthreads();
  for (int off = 1; off < 128; off <<= 1) {
    int v = (i >= off) ? buf[y][i - off] : 0;
    __syncthreads();
    buf[y][i] += v;
    __syncthreads();
  }
  if (i < kNBUK) bbase[y * kNBUK + i] = buf[y][i] - x;
  if (t == 0) { rpa[kN] = kE; rpb[kN] = kE; }
}

// k_bucket: one block per (bucket, graph). LDS histogram + pair scan ->
// writes rp segment AND scatters es via LDS cursor atomics.
__global__ __launch_bounds__(256)
void k_bucket(const int* __restrict__ cnt, const int* __restrict__ bbase,
              const unsigned* __restrict__ pay,
              int* __restrict__ rpa, int* __restrict__ rpb,
              int* __restrict__ esa, int* __restrict__ esb) {
  int b = blockIdx.x, y = blockIdx.y;
  int* rp = y ? rpb : rpa;
  int* es = y ? esb : esa;
  const unsigned* p = pay + ((size_t)y * kNBUK + b) * kCAP;
  int c = cnt[y * kNBUK + b];
  int base = bbase[y * kNBUK + b];
  __shared__ unsigned pl[kCAP];                 // 36.9KB
  __shared__ int h[512];
  __shared__ int buf[256];
  int t = threadIdx.x;
  h[t] = 0; h[t + 256] = 0;
  __syncthreads();
  for (int i = t; i < c; i += 256) {
    unsigned w = p[i];
    pl[i] = w;
    atomicAdd(&h[(w >> 16) & 511], 1);
  }
  __syncthreads();
  int a = h[2 * t], b1 = h[2 * t + 1];
  int s2 = a + b1;
  buf[t] = s2;
  __syncthreads();
  for (int off = 1; off < 256; off <<= 1) {
    int v = (t >= off) ? buf[t - off] : 0;
    __syncthreads();
    buf[t] += v;
    __syncthreads();
  }
  int ex = buf[t] - s2;                         // exclusive pair base
  int g0 = b * 512 + 2 * t;
  if (g0 < kN) rp[g0] = base + ex;
  if (g0 + 1 < kN) rp[g0 + 1] = base + ex + a;
  h[2 * t] = ex;                                // h becomes local cursors
  h[2 * t + 1] = ex + a;
  __syncthreads();
  for (int i = t; i < c; i += 256) {
    unsigned w = pl[i];
    int slot = atomicAdd(&h[(w >> 16) & 511], 1);
    es[base + slot] = (int)(w & 0xFFFFu);
  }
}

// ---------------- GAT aggregate (round-3 proven structure, per-graph) ------
// Split into TWO dispatches (y passed as arg): (1) diagnostic — each becomes
// ~64us so any hidden kernel >62us surfaces in the top-5; (2) only one
// 25.6MB feat table competes for L2 during each dispatch.
__global__ __launch_bounds__(256)
void k_agg(const int* __restrict__ rp, const int* __restrict__ es,
           const float* __restrict__ el, const float* __restrict__ er,
           const unsigned short* __restrict__ feat,
           const float* __restrict__ bias,
           float* __restrict__ za, unsigned short* __restrict__ zb,
           int y) {
  __shared__ float wls[4][512];                // 64 edges x 8 heads per wave
  __shared__ int sls[4][64];
  int nb = blockIdx.x;
  int lane = threadIdx.x & 63;
  int wave = threadIdx.x >> 6;
  int n = nb * 4 + wave;
  int hh = lane >> 3;                          // phase1 edge-slot
  int h = lane & 7;                            // phase1 head
  int half = lane >> 5;                        // phase2: which edge of pair
  int l5 = lane & 31;
  int h2 = l5 >> 2;                            // phase2 head (dims l5*8..+7)
  unsigned idx16 = (unsigned)l5 * 16u;         // byte offset in feat row
  float erh = er[n * 8 + h];
  int e0 = rp[n], e1 = rp[n + 1];
  float dsum = 0.f;
  float a0 = 0.f, a1 = 0.f, a2 = 0.f, a3 = 0.f;
  float a4 = 0.f, a5 = 0.f, a6 = 0.f, a7 = 0.f;

  for (int cb = e0; cb < e1; cb += 64) {
    int cnt = e1 - cb;
    if (cnt > 64) cnt = 64;
    // phase 1: weights -> LDS, 8 edges/iter, no lane redundancy
    for (int it = 0; it * 8 < cnt; ++it) {
      int j = it * 8 + hh;
      if (j < cnt) {
        int s = es[cb + j];
        float ev = *(const float*)((const char*)el + ((unsigned)s << 5) +
                                   ((unsigned)h << 2)) + erh;
        ev = fmaxf(ev, 0.2f * ev);             // LeakyReLU(0.2)
        float w = __expf(ev);
        wls[wave][it * 64 + lane] = w;         // == [j*8 + h]
        if (h == 0) sls[wave][j] = s;
        dsum += w;
      }
    }
    // phase 2: 2 edges/instr, 16B/lane (same-wave LDS dep, no barrier)
    int j = 0;
    for (; j + 7 < cnt; j += 8) {
#pragma unroll
      for (int p = 0; p < 4; ++p) {
        int jj = j + 2 * p + half;
        int s = sls[wave][jj];
        float w = wls[wave][jj * 8 + h2];
        us8 fv = *(const us8*)((const char*)feat + (((unsigned)s << 9) + idx16));
        a0 += w * b2f(fv[0]);
        a1 += w * b2f(fv[1]);
        a2 += w * b2f(fv[2]);
        a3 += w * b2f(fv[3]);
        a4 += w * b2f(fv[4]);
        a5 += w * b2f(fv[5]);
        a6 += w * b2f(fv[6]);
        a7 += w * b2f(fv[7]);
      }
    }
    if (j < cnt) {
#pragma unroll
      for (int p = 0; p < 4; ++p) {
        int jj = j + 2 * p + half;
        bool v = jj < cnt;
        int jc = v ? jj : j;
        int s = sls[wave][jc];
        float w = v ? wls[wave][jc * 8 + h2] : 0.f;
        us8 fv = *(const us8*)((const char*)feat + (((unsigned)s << 9) + idx16));
        a0 += w * b2f(fv[0]);
        a1 += w * b2f(fv[1]);
        a2 += w * b2f(fv[2]);
        a3 += w * b2f(fv[3]);
        a4 += w * b2f(fv[4]);
        a5 += w * b2f(fv[5]);
        a6 += w * b2f(fv[6]);
        a7 += w * b2f(fv[7]);
      }
    }
  }
  // combine halves (each half holds alternating edges' partials)
  a0 += __shfl_xor(a0, 32); a1 += __shfl_xor(a1, 32);
  a2 += __shfl_xor(a2, 32); a3 += __shfl_xor(a3, 32);
  a4 += __shfl_xor(a4, 32); a5 += __shfl_xor(a5, 32);
  a6 += __shfl_xor(a6, 32); a7 += __shfl_xor(a7, 32);
  // denom: reduce over edge-slot bits; lane i holds head i&7 total
  dsum += __shfl_xor(dsum, 8);
  dsum += __shfl_xor(dsum, 16);
  dsum += __shfl_xor(dsum, 32);
  float dh = __shfl(dsum, h2);                 // this lane's head total
  float inv = __builtin_amdgcn_rcpf(dh > 0.f ? dh : 1.f);
  f32x4 blo = *(const f32x4*)(bias + l5 * 8);
  f32x4 bhi = *(const f32x4*)(bias + l5 * 8 + 4);
  float r0 = a0 * inv + blo.x;
  float r1 = a1 * inv + blo.y;
  float r2 = a2 * inv + blo.z;
  float r3 = a3 * inv + blo.w;
  float r4 = a4 * inv + bhi.x;
  float r5 = a5 * inv + bhi.y;
  float r6 = a6 * inv + bhi.z;
  float r7 = a7 * inv + bhi.w;
  r0 = r0 > 0.f ? r0 : __expf(r0) - 1.f;       // ELU (no libm)
  r1 = r1 > 0.f ? r1 : __expf(r1) - 1.f;
  r2 = r2 > 0.f ? r2 : __expf(r2) - 1.f;
  r3 = r3 > 0.f ? r3 : __expf(r3) - 1.f;
  r4 = r4 > 0.f ? r4 : __expf(r4) - 1.f;
  r5 = r5 > 0.f ? r5 : __expf(r5) - 1.f;
  r6 = r6 > 0.f ? r6 : __expf(r6) - 1.f;
  r7 = r7 > 0.f ? r7 : __expf(r7) - 1.f;
  f32x4 lo = {r0, r1, r2, r3};
  f32x4 hi = {r4, r5, r6, r7};
  f32x4 ov = half ? hi : lo;
  if (y == 0) {
    *(f32x4*)((char*)za + (size_t)n * 1024 + l5 * 32 + half * 16) = ov;
  } else {
    us4 o;
    o.x = f2b(ov.x); o.y = f2b(ov.y); o.z = f2b(ov.z); o.w = f2b(ov.w);
    *(us4*)((char*)zb + (size_t)n * 512 + l5 * 16 + half * 8) = o;
  }
}

// ---------------- semantic scores via MFMA ---------------------------------
__global__ __launch_bounds__(256)
void k_sem(const float* __restrict__ za,
           const unsigned short* __restrict__ zb,
           const unsigned short* __restrict__ w1t,
           const float* __restrict__ b1,
           const float* __restrict__ W2,
           float* __restrict__ wacc) {
  __shared__ us8 w1l[4096];                     // 128 rows x 32 chunks, 64KB
  int t = threadIdx.x;
  for (int i = t; i < 4096; i += 256) {
    int j = i >> 5, c = i & 31;
    w1l[j * 32 + (c ^ (j & 7))] = ((const us8*)w1t)[i];
  }
  __syncthreads();
  int lane = t & 63, wave = t >> 6;
  int col = lane & 15, quad = lane >> 4;
  float b1v[8], w2v[8];
#pragma unroll
  for (int tt = 0; tt < 8; ++tt) {
    b1v[tt] = b1[tt * 16 + col];
    w2v[tt] = W2[tt * 16 + col];
  }
  int gw = blockIdx.x * 4 + wave;
  int nw = gridDim.x * 4;
  float sa = 0.f, sb = 0.f;
  for (int gt = gw; gt < 6250; gt += nw) {
    f32x4 acc[8];
#pragma unroll
    for (int tt = 0; tt < 8; ++tt) acc[tt] = (f32x4){0.f, 0.f, 0.f, 0.f};
#pragma unroll
    for (int ks = 0; ks < 8; ++ks) {
      bf16x8 a;
      if (gt < 3125) {
        const float* ap = za + (size_t)gt * 4096 + col * 256 + ks * 32 + quad * 8;
        f32x4 a0 = *(const f32x4*)ap;
        f32x4 a1 = *(const f32x4*)(ap + 4);
        a[0] = (short)f2b(a0.x); a[1] = (short)f2b(a0.y);
        a[2] = (short)f2b(a0.z); a[3] = (short)f2b(a0.w);
        a[4] = (short)f2b(a1.x); a[5] = (short)f2b(a1.y);
        a[6] = (short)f2b(a1.z); a[7] = (short)f2b(a1.w);
      } else {
        a = *(const bf16x8*)(zb + (size_t)(gt - 3125) * 4096 + col * 256 +
                             ks * 32 + quad * 8);
      }
      int c = ks * 4 + quad;
#pragma unroll
      for (int tt = 0; tt < 8; ++tt) {
        int j = tt * 16 + col;
        bf16x8 b = (bf16x8)w1l[j * 32 + (c ^ (j & 7))];
        acc[tt] = __builtin_amdgcn_mfma_f32_16x16x32_bf16(a, b, acc[tt], 0, 0, 0);
      }
    }
    float tot = 0.f;
#pragma unroll
    for (int tt = 0; tt < 8; ++tt)
#pragma unroll
      for (int r = 0; r < 4; ++r) {
        float x = acc[tt][r] + b1v[tt];
        x = fminf(fmaxf(x, -10.f), 10.f);       // clamp for exp overflow
        float ex = __expf(2.f * x);             // tanh = (e^2x-1)/(e^2x+1)
        tot += (ex - 1.f) * __builtin_amdgcn_rcpf(ex + 1.f) * w2v[tt];
      }
#pragma unroll
    for (int off = 1; off < 64; off <<= 1) tot += __shfl_xor(tot, off);
    if (gt < 3125) sa += tot; else sb += tot;
  }
  if (lane == 0) {
    if (sa != 0.f) atomicAdd(&wacc[0], sa);
    if (sb != 0.f) atomicAdd(&wacc[1], sb);
  }
}

// ---------------- beta softmax + combine (in-place over za==out) -----------
__global__ __launch_bounds__(256)
void k_combine(const float* __restrict__ za,
               const unsigned short* __restrict__ zb,
               const float* __restrict__ wacc,
               float* __restrict__ out) {
  int i = blockIdx.x * 256 + threadIdx.x;       // 3.2M groups of 4
  float wa = wacc[0] * (1.f / kN), wb = wacc[1] * (1.f / kN);
  float mx = fmaxf(wa, wb);
  float ea = __expf(wa - mx), eb = __expf(wb - mx);
  float inv = __builtin_amdgcn_rcpf(ea + eb);
  float ba = ea * inv, bb = eb * inv;
  f32x4 x = ((const f32x4*)za)[i];
  us4 yv = ((const us4*)zb)[i];
  f32x4 o;
#pragma unroll
  for (int j = 0; j < 4; ++j)
    o[j] = ba * x[j] + bb * b2f(yv[j]);
  ((f32x4*)out)[i] = o;
}

extern "C" void kernel_launch(void* const* d_in, const int* in_sizes, int n_in,
                              void* d_out, int out_size, void* d_ws, size_t ws_size,
                              hipStream_t stream) {
  const float* hin = (const float*)d_in[0];
  const int* src_a = (const int*)d_in[1];
  const int* dst_a = (const int*)d_in[2];
  const int* src_b = (const int*)d_in[3];
  const int* dst_b = (const int*)d_in[4];
  const float* W_a = (const float*)d_in[5];
  const float* al_a = (const float*)d_in[6];
  const float* ar_a = (const float*)d_in[7];
  const float* bias_a = (const float*)d_in[8];
  const float* W_b = (const float*)d_in[9];
  const float* al_b = (const float*)d_in[10];
  const float* ar_b = (const float*)d_in[11];
  const float* bias_b = (const float*)d_in[12];
  const float* sW1 = (const float*)d_in[13];
  const float* sb1 = (const float*)d_in[14];
  const float* sW2 = (const float*)d_in[15];
  float* out = (float*)d_out;

  char* wsb = (char*)d_ws;
  size_t off = 0;
  auto alloc = [&](size_t bytes) -> char* {
    char* p = wsb + off;
    off = (off + bytes + 511) & ~(size_t)511;
    return p;
  };
  // Footprint ~98 MB.
  unsigned short* feat_a = (unsigned short*)alloc((size_t)kN * 256 * 2); // 25.6MB
  unsigned short* feat_b = (unsigned short*)alloc((size_t)kN * 256 * 2); // 25.6MB
  unsigned short* z_b    = (unsigned short*)alloc((size_t)kN * 256 * 2); // 25.6MB
  float* el_a = (float*)alloc((size_t)kN * 8 * 4);
  float* er_a = (float*)alloc((size_t)kN * 8 * 4);
  float* el_b = (float*)alloc((size_t)kN * 8 * 4);
  float* er_b = (float*)alloc((size_t)kN * 8 * 4);
  unsigned short* wt_a = (unsigned short*)alloc(65536 * 2);
  unsigned short* wt_b = (unsigned short*)alloc(65536 * 2);
  unsigned short* w1t  = (unsigned short*)alloc(32768 * 2);
  int* rp_a = (int*)alloc((size_t)(kN + 1) * 4);
  int* rp_b = (int*)alloc((size_t)(kN + 1) * 4);
  int* es_a = (int*)alloc((size_t)kE * 4);
  int* es_b = (int*)alloc((size_t)kE * 4);
  unsigned* pay = (unsigned*)alloc((size_t)2 * kNBUK * kCAP * 4);  // 7.2MB
  int* cnt = (int*)alloc((size_t)2 * kNBUK * 4);
  int* bbase = (int*)alloc((size_t)2 * kNBUK * 4);
  float* wacc = (float*)alloc(2 * 4);

  hipMemsetAsync(cnt, 0, (size_t)2 * kNBUK * 4, stream);
  hipMemsetAsync(wacc, 0, 8, stream);

  k_prep<<<640, 256, 0, stream>>>(W_a, W_b, sW1, wt_a, wt_b, w1t);
  k_part<<<dim3(125, 2), 256, 0, stream>>>(src_a, dst_a, src_b, dst_b, cnt, pay);
  k_bscan<<<1, 256, 0, stream>>>(cnt, bbase, rp_a, rp_b);
  k_bucket<<<dim3(kNBUK, 2), 256, 0, stream>>>(cnt, bbase, pay,
                                               rp_a, rp_b, es_a, es_b);
  k_gemm<<<782, 512, 0, stream>>>(hin, wt_a, wt_b,
                                  al_a, ar_a, al_b, ar_b,
                                  feat_a, feat_b,
                                  el_a, er_a, el_b, er_b);
  k_agg<<<12500, 256, 0, stream>>>(rp_a, es_a, el_a, er_a, feat_a, bias_a,
                                   out, z_b, 0);
  k_agg<<<12500, 256, 0, stream>>>(rp_b, es_b, el_b, er_b, feat_b, bias_b,
                                   out, z_b, 1);
  k_sem<<<512, 256, 0, stream>>>(out, z_b, w1t, sb1, sW2, wacc);
  k_combine<<<12500, 256, 0, stream>>>(out, z_b, wacc, out);
}

// Round 10
// 444.712 us; speedup vs baseline: 1.0073x; 1.0073x over previous
//
#include <hip/hip_runtime.h>
#include <math.h>

typedef __attribute__((ext_vector_type(8))) short bf16x8;
typedef __attribute__((ext_vector_type(4))) float f32x4;
typedef __attribute__((ext_vector_type(4))) unsigned short us4;
typedef __attribute__((ext_vector_type(8))) unsigned short us8;

static constexpr int kN  = 50000;
static constexpr int kE  = 800000;
static constexpr int kNBUK = 98;     // ceil(50000/512), bucket = dst>>9
static constexpr int kCAP  = 9216;   // per-bucket payload cap (mean 8163 + 11.6 sigma)

__device__ __forceinline__ float b2f(unsigned short u) {
  union { unsigned u; float f; } x; x.u = ((unsigned)u) << 16; return x.f;
}
__device__ __forceinline__ unsigned short f2b(float f) {
  union { float f; unsigned u; } x; x.f = f;
  unsigned u = x.u;
  unsigned r = (u + 0x7fffu + ((u >> 16) & 1u)) >> 16;
  return (unsigned short)r;
}

// ---------------- fused prep: Wt_a, Wt_b (bf16 [256][256]), W1T (bf16 [128][256])
__global__ __launch_bounds__(256)
void k_prep(const float* __restrict__ Wa, const float* __restrict__ Wb,
            const float* __restrict__ W1,
            unsigned short* __restrict__ wta, unsigned short* __restrict__ wtb,
            unsigned short* __restrict__ w1t) {
  int b = blockIdx.x, t = threadIdx.x;
  if (b < 256) {
    int i = b * 256 + t, j = i >> 8, k = i & 255;
    wta[j * 256 + k] = f2b(Wa[k * 256 + j]);
  } else if (b < 512) {
    int i = (b - 256) * 256 + t, j = i >> 8, k = i & 255;
    wtb[j * 256 + k] = f2b(Wb[k * 256 + j]);
  } else {
    int i = (b - 512) * 256 + t, j = i >> 8, k = i & 255;  // j<128
    w1t[j * 256 + k] = f2b(W1[k * 128 + j]);
  }
}

// ---------------- feat = h @ W + fused el/er -------------------------------
// r7 diagnosis: 72KB LDS -> 2 blocks/CU, occupancy 17.9%, MfmaUtil 5.7% ->
// latency-starved barrier lockstep. Fix: per-metapath 64-row tiles, 8 waves
// x 32 cols (ONE head per wave). LDS = 8KB A + 32KB B = 40KB. Grid (782,2).
// launch_bounds(512,6): VGPR cap ~85 (spill-free; (512,8)'s 64-cap would
// spill the 56-reg live set) -> 3 blocks/CU, 24 waves/CU. acc 4x2 (32 VGPR).
// h re-read per metapath is L3-absorbed (r7: 51MB read -> 27MB HBM fetch)
// and we're at 12% HBM — latency hiding is the binder, not bytes.
__global__ __launch_bounds__(512, 6)
void k_gemm(const float* __restrict__ h,
            const unsigned short* __restrict__ wta,
            const unsigned short* __restrict__ wtb,
            const float* __restrict__ ala, const float* __restrict__ ara,
            const float* __restrict__ alb, const float* __restrict__ arb,
            unsigned short* __restrict__ fa, unsigned short* __restrict__ fb,
            float* __restrict__ ela, float* __restrict__ era,
            float* __restrict__ elb, float* __restrict__ erb) {
  __shared__ us8 la[64 * 8];                   // 8KB
  __shared__ us8 lbb[256 * 8];                 // 32KB
  const int z = blockIdx.y;
  const unsigned short* wt = z ? wtb : wta;
  unsigned short* f = z ? fb : fa;
  const float* al = z ? alb : ala;
  const float* ar = z ? arb : ara;
  float* el = z ? elb : ela;
  float* er = z ? erb : era;
  const int m0 = blockIdx.x * 64;
  const int t = threadIdx.x;
  const int lane = t & 63;
  const int wave = t >> 6;                     // 0..7 == head
  const int col = lane & 15;
  const int quad = lane >> 4;
  const int nw = wave * 32;                    // this wave's 32 cols
  f32x4 acc[4][2];
#pragma unroll
  for (int i = 0; i < 4; ++i)
#pragma unroll
    for (int j = 0; j < 2; ++j) acc[i][j] = (f32x4){0.f, 0.f, 0.f, 0.f};

  for (int ks = 0; ks < 4; ++ks) {
    const int k0 = ks * 64;
    __syncthreads();
    // stage A: 64 rows x 64 k, fp32 -> bf16. 1024 8B-units, 2 iters.
#pragma unroll
    for (int i = 0; i < 2; ++i) {
      int idx = i * 512 + t;
      int r = idx >> 4, g = (idx >> 1) & 7, half = idx & 1;
      int gr = m0 + r;
      f32x4 v = {0.f, 0.f, 0.f, 0.f};
      if (gr < kN) v = *(const f32x4*)(h + (size_t)gr * 256 + k0 + g * 8 + half * 4);
      us4 o;
      o.x = f2b(v.x); o.y = f2b(v.y); o.z = f2b(v.z); o.w = f2b(v.w);
      *(us4*)((unsigned short*)&la[r * 8 + (g ^ (r & 7))] + half * 4) = o;
    }
    // stage B: 256 rows x 64 k bf16. 2048 16B-units, 4 iters.
#pragma unroll
    for (int i = 0; i < 4; ++i) {
      int idx = i * 512 + t;
      int r = idx >> 3, g = idx & 7;
      lbb[r * 8 + (g ^ (r & 7))] = *(const us8*)(wt + r * 256 + k0 + g * 8);
    }
    __syncthreads();
#pragma unroll
    for (int k32 = 0; k32 < 64; k32 += 32) {
      const int cg = (k32 >> 3) + quad;
      bf16x8 af[4], bf[2];
#pragma unroll
      for (int s = 0; s < 4; ++s) {
        int arow = s * 16 + col;
        af[s] = (bf16x8)la[arow * 8 + (cg ^ (arow & 7))];
      }
#pragma unroll
      for (int j = 0; j < 2; ++j) {
        int brow = nw + j * 16 + col;
        bf[j] = (bf16x8)lbb[brow * 8 + (cg ^ (brow & 7))];
      }
#pragma unroll
      for (int i = 0; i < 4; ++i)
#pragma unroll
        for (int j = 0; j < 2; ++j)
          acc[i][j] = __builtin_amdgcn_mfma_f32_16x16x32_bf16(af[i], bf[j],
                                                              acc[i][j], 0, 0, 0);
    }
  }
  // epilogue 1: feat store (C row = quad*4+reg, col = lane&15)
#pragma unroll
  for (int i = 0; i < 4; ++i) {
#pragma unroll
    for (int r = 0; r < 4; ++r) {
      int row = m0 + i * 16 + quad * 4 + r;
      if (row < kN) {
#pragma unroll
        for (int j = 0; j < 2; ++j)
          f[(size_t)row * 256 + nw + j * 16 + col] = f2b(acc[i][j][r]);
      }
    }
  }
  // epilogue 2: el/er for this wave's single head (cols nw..nw+31)
  float alv[2], arv[2];
#pragma unroll
  for (int j = 0; j < 2; ++j) {
    alv[j] = al[nw + j * 16 + col];
    arv[j] = ar[nw + j * 16 + col];
  }
#pragma unroll
  for (int i = 0; i < 4; ++i) {
#pragma unroll
    for (int r = 0; r < 4; ++r) {
      float pl = acc[i][0][r] * alv[0] + acc[i][1][r] * alv[1];
      float pr = acc[i][0][r] * arv[0] + acc[i][1][r] * arv[1];
#pragma unroll
      for (int off = 1; off < 16; off <<= 1) {
        pl += __shfl_xor(pl, off);
        pr += __shfl_xor(pr, off);
      }
      int row = m0 + i * 16 + quad * 4 + r;
      if (col == 0 && row < kN) {
        el[row * 8 + wave] = pl;
        er[row * 8 + wave] = pr;
      }
    }
  }
}

// ---------------- CSR build via radix partition ----------------------------
__global__ __launch_bounds__(256)
void k_part(const int* __restrict__ sa, const int* __restrict__ da,
            const int* __restrict__ sb, const int* __restrict__ db,
            int* __restrict__ cnt, unsigned* __restrict__ pay) {
  int y = blockIdx.y;
  const int* s = y ? sb : sa;
  const int* d = y ? db : da;
  unsigned* p = pay + (size_t)y * kNBUK * kCAP;
  int* cn = cnt + y * kNBUK;
  __shared__ unsigned stash[6400];              // 25.6KB
  __shared__ int h[kNBUK];
  int t = threadIdx.x;
  if (t < kNBUK) h[t] = 0;
  __syncthreads();
  int e0 = blockIdx.x * 6400;
#pragma unroll 5
  for (int it = 0; it < 25; ++it) {
    int e = e0 + it * 256 + t;
    int sv = s[e], dv = d[e];
    int b = dv >> 9;
    stash[it * 256 + t] = (unsigned)sv | ((unsigned)(dv & 511) << 16) |
                          ((unsigned)b << 25);
    atomicAdd(&h[b], 1);
  }
  __syncthreads();
  if (t < kNBUK) h[t] = atomicAdd(&cn[t], h[t]);  // h becomes block's cursor
  __syncthreads();
#pragma unroll 5
  for (int it = 0; it < 25; ++it) {
    unsigned w = stash[it * 256 + t];
    int b = w >> 25;
    int slot = atomicAdd(&h[b], 1);
    p[b * kCAP + slot] = w & 0x1FFFFFFu;
  }
}

// k_bscan: exclusive scan of 2x98 bucket counts -> global es/rp bases.
__global__ __launch_bounds__(256)
void k_bscan(const int* __restrict__ cnt, int* __restrict__ bbase,
             int* __restrict__ rpa, int* __restrict__ rpb) {
  __shared__ int buf[2][128];
  int t = threadIdx.x;
  int y = t >> 7, i = t & 127;
  int x = (i < kNBUK) ? cnt[y * kNBUK + i] : 0;
  buf[y][i] = x;
  __syncthreads();
  for (int off = 1; off < 128; off <<= 1) {
    int v = (i >= off) ? buf[y][i - off] : 0;
    __syncthreads();
    buf[y][i] += v;
    __syncthreads();
  }
  if (i < kNBUK) bbase[y * kNBUK + i] = buf[y][i] - x;
  if (t == 0) { rpa[kN] = kE; rpb[kN] = kE; }
}

// k_bucket: one block per (bucket, graph). LDS histogram + pair scan ->
// writes rp segment AND scatters es via LDS cursor atomics.
__global__ __launch_bounds__(256)
void k_bucket(const int* __restrict__ cnt, const int* __restrict__ bbase,
              const unsigned* __restrict__ pay,
              int* __restrict__ rpa, int* __restrict__ rpb,
              int* __restrict__ esa, int* __restrict__ esb) {
  int b = blockIdx.x, y = blockIdx.y;
  int* rp = y ? rpb : rpa;
  int* es = y ? esb : esa;
  const unsigned* p = pay + ((size_t)y * kNBUK + b) * kCAP;
  int c = cnt[y * kNBUK + b];
  int base = bbase[y * kNBUK + b];
  __shared__ unsigned pl[kCAP];                 // 36.9KB
  __shared__ int h[512];
  __shared__ int buf[256];
  int t = threadIdx.x;
  h[t] = 0; h[t + 256] = 0;
  __syncthreads();
  for (int i = t; i < c; i += 256) {
    unsigned w = p[i];
    pl[i] = w;
    atomicAdd(&h[(w >> 16) & 511], 1);
  }
  __syncthreads();
  int a = h[2 * t], b1 = h[2 * t + 1];
  int s2 = a + b1;
  buf[t] = s2;
  __syncthreads();
  for (int off = 1; off < 256; off <<= 1) {
    int v = (t >= off) ? buf[t - off] : 0;
    __syncthreads();
    buf[t] += v;
    __syncthreads();
  }
  int ex = buf[t] - s2;                         // exclusive pair base
  int g0 = b * 512 + 2 * t;
  if (g0 < kN) rp[g0] = base + ex;
  if (g0 + 1 < kN) rp[g0 + 1] = base + ex + a;
  h[2 * t] = ex;                                // h becomes local cursors
  h[2 * t + 1] = ex + a;
  __syncthreads();
  for (int i = t; i < c; i += 256) {
    unsigned w = pl[i];
    int slot = atomicAdd(&h[(w >> 16) & 511], 1);
    es[base + slot] = (int)(w & 0xFFFFu);
  }
}

// ---------------- GAT aggregate (round-3 proven structure, per-graph) ------
__global__ __launch_bounds__(256)
void k_agg(const int* __restrict__ rp, const int* __restrict__ es,
           const float* __restrict__ el, const float* __restrict__ er,
           const unsigned short* __restrict__ feat,
           const float* __restrict__ bias,
           float* __restrict__ za, unsigned short* __restrict__ zb,
           int y) {
  __shared__ float wls[4][512];                // 64 edges x 8 heads per wave
  __shared__ int sls[4][64];
  int nb = blockIdx.x;
  int lane = threadIdx.x & 63;
  int wave = threadIdx.x >> 6;
  int n = nb * 4 + wave;
  int hh = lane >> 3;                          // phase1 edge-slot
  int h = lane & 7;                            // phase1 head
  int half = lane >> 5;                        // phase2: which edge of pair
  int l5 = lane & 31;
  int h2 = l5 >> 2;                            // phase2 head (dims l5*8..+7)
  unsigned idx16 = (unsigned)l5 * 16u;         // byte offset in feat row
  float erh = er[n * 8 + h];
  int e0 = rp[n], e1 = rp[n + 1];
  float dsum = 0.f;
  float a0 = 0.f, a1 = 0.f, a2 = 0.f, a3 = 0.f;
  float a4 = 0.f, a5 = 0.f, a6 = 0.f, a7 = 0.f;

  for (int cb = e0; cb < e1; cb += 64) {
    int cnt = e1 - cb;
    if (cnt > 64) cnt = 64;
    // phase 1: weights -> LDS, 8 edges/iter, no lane redundancy
    for (int it = 0; it * 8 < cnt; ++it) {
      int j = it * 8 + hh;
      if (j < cnt) {
        int s = es[cb + j];
        float ev = *(const float*)((const char*)el + ((unsigned)s << 5) +
                                   ((unsigned)h << 2)) + erh;
        ev = fmaxf(ev, 0.2f * ev);             // LeakyReLU(0.2)
        float w = __expf(ev);
        wls[wave][it * 64 + lane] = w;         // == [j*8 + h]
        if (h == 0) sls[wave][j] = s;
        dsum += w;
      }
    }
    // phase 2: 2 edges/instr, 16B/lane (same-wave LDS dep, no barrier)
    int j = 0;
    for (; j + 7 < cnt; j += 8) {
#pragma unroll
      for (int p = 0; p < 4; ++p) {
        int jj = j + 2 * p + half;
        int s = sls[wave][jj];
        float w = wls[wave][jj * 8 + h2];
        us8 fv = *(const us8*)((const char*)feat + (((unsigned)s << 9) + idx16));
        a0 += w * b2f(fv[0]);
        a1 += w * b2f(fv[1]);
        a2 += w * b2f(fv[2]);
        a3 += w * b2f(fv[3]);
        a4 += w * b2f(fv[4]);
        a5 += w * b2f(fv[5]);
        a6 += w * b2f(fv[6]);
        a7 += w * b2f(fv[7]);
      }
    }
    if (j < cnt) {
#pragma unroll
      for (int p = 0; p < 4; ++p) {
        int jj = j + 2 * p + half;
        bool v = jj < cnt;
        int jc = v ? jj : j;
        int s = sls[wave][jc];
        float w = v ? wls[wave][jc * 8 + h2] : 0.f;
        us8 fv = *(const us8*)((const char*)feat + (((unsigned)s << 9) + idx16));
        a0 += w * b2f(fv[0]);
        a1 += w * b2f(fv[1]);
        a2 += w * b2f(fv[2]);
        a3 += w * b2f(fv[3]);
        a4 += w * b2f(fv[4]);
        a5 += w * b2f(fv[5]);
        a6 += w * b2f(fv[6]);
        a7 += w * b2f(fv[7]);
      }
    }
  }
  // combine halves (each half holds alternating edges' partials)
  a0 += __shfl_xor(a0, 32); a1 += __shfl_xor(a1, 32);
  a2 += __shfl_xor(a2, 32); a3 += __shfl_xor(a3, 32);
  a4 += __shfl_xor(a4, 32); a5 += __shfl_xor(a5, 32);
  a6 += __shfl_xor(a6, 32); a7 += __shfl_xor(a7, 32);
  // denom: reduce over edge-slot bits; lane i holds head i&7 total
  dsum += __shfl_xor(dsum, 8);
  dsum += __shfl_xor(dsum, 16);
  dsum += __shfl_xor(dsum, 32);
  float dh = __shfl(dsum, h2);                 // this lane's head total
  float inv = __builtin_amdgcn_rcpf(dh > 0.f ? dh : 1.f);
  f32x4 blo = *(const f32x4*)(bias + l5 * 8);
  f32x4 bhi = *(const f32x4*)(bias + l5 * 8 + 4);
  float r0 = a0 * inv + blo.x;
  float r1 = a1 * inv + blo.y;
  float r2 = a2 * inv + blo.z;
  float r3 = a3 * inv + blo.w;
  float r4 = a4 * inv + bhi.x;
  float r5 = a5 * inv + bhi.y;
  float r6 = a6 * inv + bhi.z;
  float r7 = a7 * inv + bhi.w;
  r0 = r0 > 0.f ? r0 : __expf(r0) - 1.f;       // ELU (no libm)
  r1 = r1 > 0.f ? r1 : __expf(r1) - 1.f;
  r2 = r2 > 0.f ? r2 : __expf(r2) - 1.f;
  r3 = r3 > 0.f ? r3 : __expf(r3) - 1.f;
  r4 = r4 > 0.f ? r4 : __expf(r4) - 1.f;
  r5 = r5 > 0.f ? r5 : __expf(r5) - 1.f;
  r6 = r6 > 0.f ? r6 : __expf(r6) - 1.f;
  r7 = r7 > 0.f ? r7 : __expf(r7) - 1.f;
  f32x4 lo = {r0, r1, r2, r3};
  f32x4 hi = {r4, r5, r6, r7};
  f32x4 ov = half ? hi : lo;
  if (y == 0) {
    *(f32x4*)((char*)za + (size_t)n * 1024 + l5 * 32 + half * 16) = ov;
  } else {
    us4 o;
    o.x = f2b(ov.x); o.y = f2b(ov.y); o.z = f2b(ov.z); o.w = f2b(ov.w);
    *(us4*)((char*)zb + (size_t)n * 512 + l5 * 16 + half * 8) = o;
  }
}

// ---------------- semantic scores via MFMA ---------------------------------
__global__ __launch_bounds__(256)
void k_sem(const float* __restrict__ za,
           const unsigned short* __restrict__ zb,
           const unsigned short* __restrict__ w1t,
           const float* __restrict__ b1,
           const float* __restrict__ W2,
           float* __restrict__ wacc) {
  __shared__ us8 w1l[4096];                     // 128 rows x 32 chunks, 64KB
  int t = threadIdx.x;
  for (int i = t; i < 4096; i += 256) {
    int j = i >> 5, c = i & 31;
    w1l[j * 32 + (c ^ (j & 7))] = ((const us8*)w1t)[i];
  }
  __syncthreads();
  int lane = t & 63, wave = t >> 6;
  int col = lane & 15, quad = lane >> 4;
  float b1v[8], w2v[8];
#pragma unroll
  for (int tt = 0; tt < 8; ++tt) {
    b1v[tt] = b1[tt * 16 + col];
    w2v[tt] = W2[tt * 16 + col];
  }
  int gw = blockIdx.x * 4 + wave;
  int nw = gridDim.x * 4;
  float sa = 0.f, sb = 0.f;
  for (int gt = gw; gt < 6250; gt += nw) {
    f32x4 acc[8];
#pragma unroll
    for (int tt = 0; tt < 8; ++tt) acc[tt] = (f32x4){0.f, 0.f, 0.f, 0.f};
#pragma unroll
    for (int ks = 0; ks < 8; ++ks) {
      bf16x8 a;
      if (gt < 3125) {
        const float* ap = za + (size_t)gt * 4096 + col * 256 + ks * 32 + quad * 8;
        f32x4 a0 = *(const f32x4*)ap;
        f32x4 a1 = *(const f32x4*)(ap + 4);
        a[0] = (short)f2b(a0.x); a[1] = (short)f2b(a0.y);
        a[2] = (short)f2b(a0.z); a[3] = (short)f2b(a0.w);
        a[4] = (short)f2b(a1.x); a[5] = (short)f2b(a1.y);
        a[6] = (short)f2b(a1.z); a[7] = (short)f2b(a1.w);
      } else {
        a = *(const bf16x8*)(zb + (size_t)(gt - 3125) * 4096 + col * 256 +
                             ks * 32 + quad * 8);
      }
      int c = ks * 4 + quad;
#pragma unroll
      for (int tt = 0; tt < 8; ++tt) {
        int j = tt * 16 + col;
        bf16x8 b = (bf16x8)w1l[j * 32 + (c ^ (j & 7))];
        acc[tt] = __builtin_amdgcn_mfma_f32_16x16x32_bf16(a, b, acc[tt], 0, 0, 0);
      }
    }
    float tot = 0.f;
#pragma unroll
    for (int tt = 0; tt < 8; ++tt)
#pragma unroll
      for (int r = 0; r < 4; ++r) {
        float x = acc[tt][r] + b1v[tt];
        x = fminf(fmaxf(x, -10.f), 10.f);       // clamp for exp overflow
        float ex = __expf(2.f * x);             // tanh = (e^2x-1)/(e^2x+1)
        tot += (ex - 1.f) * __builtin_amdgcn_rcpf(ex + 1.f) * w2v[tt];
      }
#pragma unroll
    for (int off = 1; off < 64; off <<= 1) tot += __shfl_xor(tot, off);
    if (gt < 3125) sa += tot; else sb += tot;
  }
  if (lane == 0) {
    if (sa != 0.f) atomicAdd(&wacc[0], sa);
    if (sb != 0.f) atomicAdd(&wacc[1], sb);
  }
}

// ---------------- beta softmax + combine (in-place over za==out) -----------
__global__ __launch_bounds__(256)
void k_combine(const float* __restrict__ za,
               const unsigned short* __restrict__ zb,
               const float* __restrict__ wacc,
               float* __restrict__ out) {
  int i = blockIdx.x * 256 + threadIdx.x;       // 3.2M groups of 4
  float wa = wacc[0] * (1.f / kN), wb = wacc[1] * (1.f / kN);
  float mx = fmaxf(wa, wb);
  float ea = __expf(wa - mx), eb = __expf(wb - mx);
  float inv = __builtin_amdgcn_rcpf(ea + eb);
  float ba = ea * inv, bb = eb * inv;
  f32x4 x = ((const f32x4*)za)[i];
  us4 yv = ((const us4*)zb)[i];
  f32x4 o;
#pragma unroll
  for (int j = 0; j < 4; ++j)
    o[j] = ba * x[j] + bb * b2f(yv[j]);
  ((f32x4*)out)[i] = o;
}

extern "C" void kernel_launch(void* const* d_in, const int* in_sizes, int n_in,
                              void* d_out, int out_size, void* d_ws, size_t ws_size,
                              hipStream_t stream) {
  const float* hin = (const float*)d_in[0];
  const int* src_a = (const int*)d_in[1];
  const int* dst_a = (const int*)d_in[2];
  const int* src_b = (const int*)d_in[3];
  const int* dst_b = (const int*)d_in[4];
  const float* W_a = (const float*)d_in[5];
  const float* al_a = (const float*)d_in[6];
  const float* ar_a = (const float*)d_in[7];
  const float* bias_a = (const float*)d_in[8];
  const float* W_b = (const float*)d_in[9];
  const float* al_b = (const float*)d_in[10];
  const float* ar_b = (const float*)d_in[11];
  const float* bias_b = (const float*)d_in[12];
  const float* sW1 = (const float*)d_in[13];
  const float* sb1 = (const float*)d_in[14];
  const float* sW2 = (const float*)d_in[15];
  float* out = (float*)d_out;

  char* wsb = (char*)d_ws;
  size_t off = 0;
  auto alloc = [&](size_t bytes) -> char* {
    char* p = wsb + off;
    off = (off + bytes + 511) & ~(size_t)511;
    return p;
  };
  // Footprint ~98 MB.
  unsigned short* feat_a = (unsigned short*)alloc((size_t)kN * 256 * 2); // 25.6MB
  unsigned short* feat_b = (unsigned short*)alloc((size_t)kN * 256 * 2); // 25.6MB
  unsigned short* z_b    = (unsigned short*)alloc((size_t)kN * 256 * 2); // 25.6MB
  float* el_a = (float*)alloc((size_t)kN * 8 * 4);
  float* er_a = (float*)alloc((size_t)kN * 8 * 4);
  float* el_b = (float*)alloc((size_t)kN * 8 * 4);
  float* er_b = (float*)alloc((size_t)kN * 8 * 4);
  unsigned short* wt_a = (unsigned short*)alloc(65536 * 2);
  unsigned short* wt_b = (unsigned short*)alloc(65536 * 2);
  unsigned short* w1t  = (unsigned short*)alloc(32768 * 2);
  int* rp_a = (int*)alloc((size_t)(kN + 1) * 4);
  int* rp_b = (int*)alloc((size_t)(kN + 1) * 4);
  int* es_a = (int*)alloc((size_t)kE * 4);
  int* es_b = (int*)alloc((size_t)kE * 4);
  unsigned* pay = (unsigned*)alloc((size_t)2 * kNBUK * kCAP * 4);  // 7.2MB
  int* cnt = (int*)alloc((size_t)2 * kNBUK * 4);
  int* bbase = (int*)alloc((size_t)2 * kNBUK * 4);
  float* wacc = (float*)alloc(2 * 4);

  hipMemsetAsync(cnt, 0, (size_t)2 * kNBUK * 4, stream);
  hipMemsetAsync(wacc, 0, 8, stream);

  k_prep<<<640, 256, 0, stream>>>(W_a, W_b, sW1, wt_a, wt_b, w1t);
  k_part<<<dim3(125, 2), 256, 0, stream>>>(src_a, dst_a, src_b, dst_b, cnt, pay);
  k_bscan<<<1, 256, 0, stream>>>(cnt, bbase, rp_a, rp_b);
  k_bucket<<<dim3(kNBUK, 2), 256, 0, stream>>>(cnt, bbase, pay,
                                               rp_a, rp_b, es_a, es_b);
  k_gemm<<<dim3(782, 2), 512, 0, stream>>>(hin, wt_a, wt_b,
                                           al_a, ar_a, al_b, ar_b,
                                           feat_a, feat_b,
                                           el_a, er_a, el_b, er_b);
  k_agg<<<12500, 256, 0, stream>>>(rp_a, es_a, el_a, er_a, feat_a, bias_a,
                                   out, z_b, 0);
  k_agg<<<12500, 256, 0, stream>>>(rp_b, es_b, el_b, er_b, feat_b, bias_b,
                                   out, z_b, 1);
  k_sem<<<512, 256, 0, stream>>>(out, z_b, w1t, sb1, sW2, wacc);
  k_combine<<<12500, 256, 0, stream>>>(out, z_b, wacc, out);
}